// Round 9
// baseline (441.578 us; speedup 1.0000x reference)
//
#include <hip/hip_runtime.h>

// Problem constants (reference: S=Q=4096, E=D=2048, all fp32 in/out)
#define S_SEQ 4096
#define Q_SEQ 4096
#define E_DIM 2048
#define D_DIM 2048

typedef __bf16 bf16;
typedef __bf16 bf16x4 __attribute__((ext_vector_type(4)));
typedef __bf16 bf16x8 __attribute__((ext_vector_type(8)));
typedef float f32x4 __attribute__((ext_vector_type(4)));

// ---------------------------------------------------------------------------
// merged cast: 6 segments fp32 -> bf16, grid-stride (r8: was 49152 tiny
// blocks of 4KB each -> launch-overhead-bound; now 3072 blocks x 8-16 iters).
// ---------------------------------------------------------------------------
__global__ __launch_bounds__(256) void cast6(
    const float* __restrict__ i0, const float* __restrict__ i1,
    const float* __restrict__ i2, const float* __restrict__ i3,
    const float* __restrict__ i4, const float* __restrict__ i5,
    bf16* __restrict__ o0, bf16* __restrict__ o1, bf16* __restrict__ o2,
    bf16* __restrict__ o3, bf16* __restrict__ o4, bf16* __restrict__ o5) {
  const float* in;
  bf16* out;
  int n4;
  switch (blockIdx.y) {
    case 0: in = i0; out = o0; n4 = (S_SEQ * E_DIM) / 4; break;
    case 1: in = i1; out = o1; n4 = (S_SEQ * E_DIM) / 4; break;
    case 2: in = i2; out = o2; n4 = (S_SEQ * E_DIM) / 4; break;
    case 3: in = i3; out = o3; n4 = (D_DIM * E_DIM) / 4; break;
    case 4: in = i4; out = o4; n4 = (D_DIM * E_DIM) / 4; break;
    default: in = i5; out = o5; n4 = (D_DIM * E_DIM) / 4; break;
  }
  const int stride = 512 * 256;  // gridDim.x * blockDim.x
#pragma unroll 2
  for (int i = blockIdx.x * 256 + threadIdx.x; i < n4; i += stride) {
    float4 v = reinterpret_cast<const float4*>(in)[i];
    bf16x4 o;
    o[0] = (bf16)v.x; o[1] = (bf16)v.y; o[2] = (bf16)v.z; o[3] = (bf16)v.w;
    *reinterpret_cast<bf16x4*>(out + 4 * (size_t)i) = o;
  }
}

// ---------------------------------------------------------------------------
// async global->LDS 16B (wave-uniform lds base + lane*16 scatter)
// ---------------------------------------------------------------------------
__device__ __forceinline__ void async_copy16(const bf16* g, bf16* l) {
  __builtin_amdgcn_global_load_lds(
      (const __attribute__((address_space(1))) void*)g,
      (__attribute__((address_space(3))) void*)l, 16, 0, 0);
}

// ---------------------------------------------------------------------------
// XCD-aware tile remaps. Both bijective; 4(m) x 2(n) XCD grid.
// remap32: m-tiles of 128 (mt=32).  remap16: m-tiles of 256 (mt=16).
// ---------------------------------------------------------------------------
__device__ __forceinline__ void xcd_remap32(int id, int nt, int& m, int& n) {
  int xcd = id & 7;
  int lid = id >> 3;
  m = (xcd & 3) * 8 + (lid & 7);
  n = (xcd >> 2) * (nt >> 1) + (lid >> 3);
}
__device__ __forceinline__ void xcd_remap16(int id, int nt, int& m, int& n) {
  int xcd = id & 7;
  int lid = id >> 3;
  m = (xcd & 3) * 4 + (lid & 3);
  n = (xcd >> 2) * (nt >> 1) + (lid >> 2);
}

// ===========================================================================
// BODY A (r1 champion, proj): single-buffer 128x128, BK=64, 4 waves (2x2),
// wave tile 64x64. 32 KB LDS -> ~2.6 blocks/CU; latency hiding via implicit
// multi-block overlap (m114). Verified 97-106 us / MfmaUtil 45-49%.
// Explicit pipelining attempts (r2 8ph, r3 4ph, r4 dbuf) all LOST to this by
// cutting co-residency — do not re-attempt without template-exact geometry.
// ===========================================================================
template <int EPI>
__device__ __forceinline__ void gemm_body_sb(
    const bf16* __restrict__ A, int lda,
    const bf16* __restrict__ B, int ldb,
    void* __restrict__ C, int ldc,
    const float* __restrict__ aux, float scale, int K, int mBase, int nBase) {
  __shared__ __align__(16) bf16 Als[128 * 64];   // 16 KB
  __shared__ __align__(16) bf16 Bls[128 * 64];   // 16 KB

  const int tid  = threadIdx.x;
  const int wave = tid >> 6;
  const int lane = tid & 63;
  const int quad = lane >> 4;   // 0..3
  const int lrow = lane & 15;   // 0..15
  const int wRow = (wave >> 1) * 64;
  const int wCol = (wave & 1) * 64;

  f32x4 acc[4][4];
#pragma unroll
  for (int i = 0; i < 4; ++i)
#pragma unroll
    for (int j = 0; j < 4; ++j) {
      f32x4 z = {0.f, 0.f, 0.f, 0.f};
      acc[i][j] = z;
    }

  for (int k0 = 0; k0 < K; k0 += 64) {
#pragma unroll
    for (int c = 0; c < 4; ++c) {
      int chunk = c * 256 + tid;
      int row = chunk >> 3;
      int kc = (chunk & 7) ^ (row & 7);
      const bf16* g = A + (size_t)(mBase + row) * lda + k0 + kc * 8;
      async_copy16(g, Als + (size_t)(c * 256 + wave * 64) * 8);
    }
#pragma unroll
    for (int c = 0; c < 4; ++c) {
      int chunk = c * 256 + tid;
      int row = chunk >> 3;
      int kc = (chunk & 7) ^ (row & 7);
      const bf16* g = B + (size_t)(nBase + row) * ldb + k0 + kc * 8;
      async_copy16(g, Bls + (size_t)(c * 256 + wave * 64) * 8);
    }
    __syncthreads();  // drains vmcnt: LDS tiles ready

#pragma unroll
    for (int kk = 0; kk < 2; ++kk) {
      bf16x8 af[4], bfr[4];
#pragma unroll
      for (int i = 0; i < 4; ++i) {
        int r = wRow + i * 16 + lrow;
        int slot = (kk * 4 + quad) ^ (r & 7);
        af[i] = *(const bf16x8*)(Als + (size_t)r * 64 + slot * 8);
      }
#pragma unroll
      for (int j = 0; j < 4; ++j) {
        int r = wCol + j * 16 + lrow;
        int slot = (kk * 4 + quad) ^ (r & 7);
        bfr[j] = *(const bf16x8*)(Bls + (size_t)r * 64 + slot * 8);
      }
#pragma unroll
      for (int i = 0; i < 4; ++i)
#pragma unroll
        for (int j = 0; j < 4; ++j)
          acc[i][j] = __builtin_amdgcn_mfma_f32_16x16x32_bf16(af[i], bfr[j], acc[i][j], 0, 0, 0);
    }
    __syncthreads();  // compute done; safe to overwrite LDS next iter
  }

  // epilogue. C/D layout (verified m89/m91): col=lane&15, row=quad*4+reg
  float rinv[4][4];
  if (EPI == 2) {
#pragma unroll
    for (int i = 0; i < 4; ++i)
#pragma unroll
      for (int r = 0; r < 4; ++r)
        rinv[i][r] = aux[mBase + wRow + i * 16 + quad * 4 + r];
  }
#pragma unroll
  for (int j = 0; j < 4; ++j) {
    const int cn = nBase + wCol + j * 16 + lrow;
    float bj = 0.f;
    if (EPI == 0) bj = aux[cn];
#pragma unroll
    for (int i = 0; i < 4; ++i) {
      const int rbase = mBase + wRow + i * 16 + quad * 4;
#pragma unroll
      for (int r = 0; r < 4; ++r) {
        if (EPI == 0)
          ((bf16*)C)[(size_t)(rbase + r) * ldc + cn] = (bf16)(acc[i][j][r] + bj);
        else if (EPI == 1)
          ((bf16*)C)[(size_t)(rbase + r) * ldc + cn] =
              (bf16)__expf(acc[i][j][r] * scale);
        else
          ((float*)C)[(size_t)(rbase + r) * ldc + cn] = acc[i][j][r] * rinv[i][r];
      }
    }
  }
}

// ===========================================================================
// BODY B (r3, qk/pv): 4-phase counted-vmcnt 256x128, BK=64, 8 waves (4x2),
// wave tile 64x64. 96 KB LDS -> 1 block/CU. Verified correct r3/r6/r7.
// EPI=1: epilogue emits per-row partial sums of the bf16-rounded E values
//        over this block's wave 64-col slice to psum[row*64+col64]
//        (non-atomic, disjoint addresses, no init needed).
// EPI=2 (r8): computes inv[row] = 1/sum(psum[row][0..63]) for its own 256
//        rows in the prologue (psum is L2/L3-resident, 16KB/block) into
//        LDS inv_s — replaces the separate rowsum2 dispatch. Same per-row
//        summation order as rowsum2 -> bitwise-identical inv.
// ===========================================================================
__device__ __forceinline__ void stage_half(const bf16* __restrict__ G, int ld,
                                           int grow0, int k0, bf16* lds,
                                           int wave, int lane) {
#pragma unroll
  for (int s = 0; s < 2; ++s) {
    int c = (wave * 2 + s) * 64 + lane;  // 16B-chunk index within half, 0..1023
    int row = c >> 3;                    // 0..127 (8 chunks per 64-col row)
    int kc = (c & 7) ^ (row & 7);        // swizzled k-chunk for this slot
    const bf16* g = G + (size_t)(grow0 + row) * ld + k0 + kc * 8;
    async_copy16(g, lds + (size_t)(wave * 2 + s) * 512);
  }
}

#define BARRIER __builtin_amdgcn_s_barrier()
#define LGKM0 asm volatile("s_waitcnt lgkmcnt(0)" ::: "memory")
#define VMCNT2 asm volatile("s_waitcnt vmcnt(2)" ::: "memory")
#define VMCNT0 asm volatile("s_waitcnt vmcnt(0)" ::: "memory")

#define RD_A(buf, IP)                                                         \
  _Pragma("unroll") for (int ii = 0; ii < 2; ++ii)                            \
  _Pragma("unroll") for (int kk = 0; kk < 2; ++kk)                            \
      aR[ii][kk] = *(const bf16x8*)(&Als[buf][(size_t)(wRow + ((IP)*2 + ii) * 16 + lrow) * 64 + slotk[kk] * 8]);

#define RD_B(buf, JP, dst)                                                    \
  _Pragma("unroll") for (int jj = 0; jj < 2; ++jj)                            \
  _Pragma("unroll") for (int kk = 0; kk < 2; ++kk)                            \
      dst[jj][kk] = *(const bf16x8*)(&Bls[buf][(size_t)(wCol + ((JP)*2 + jj) * 16 + lrow) * 64 + slotk[kk] * 8]);

#define MMA16(IP)                                                              \
  __builtin_amdgcn_s_setprio(1);                                               \
  _Pragma("unroll") for (int jj = 0; jj < 2; ++jj)                             \
  _Pragma("unroll") for (int ii = 0; ii < 2; ++ii)                             \
  _Pragma("unroll") for (int kk = 0; kk < 2; ++kk)                             \
      acc[(IP)*2 + ii][jj] = __builtin_amdgcn_mfma_f32_16x16x32_bf16(          \
          aR[ii][kk], b0[jj][kk], acc[(IP)*2 + ii][jj], 0, 0, 0);              \
  _Pragma("unroll") for (int jj = 0; jj < 2; ++jj)                             \
  _Pragma("unroll") for (int ii = 0; ii < 2; ++ii)                             \
  _Pragma("unroll") for (int kk = 0; kk < 2; ++kk)                             \
      acc[(IP)*2 + ii][2 + jj] = __builtin_amdgcn_mfma_f32_16x16x32_bf16(      \
          aR[ii][kk], b1[jj][kk], acc[(IP)*2 + ii][2 + jj], 0, 0, 0);          \
  __builtin_amdgcn_s_setprio(0)

template <int EPI>
__device__ __forceinline__ void gemm_body_4ph(
    const bf16* __restrict__ A, int lda,
    const bf16* __restrict__ B, int ldb,
    void* __restrict__ C, int ldc,
    float scale, int K, int mBase, int nBase,
    float* __restrict__ psum) {
  __shared__ __align__(16) bf16 Als[2][256 * 64];  // 64 KB
  __shared__ __align__(16) bf16 Bls[2][128 * 64];  // 32 KB
  __shared__ float inv_s[256];                     // 1 KB (EPI=2 only)

  const int tid  = threadIdx.x;
  const int wave = tid >> 6;   // 0..7
  const int lane = tid & 63;
  const int quad = lane >> 4;  // 0..3
  const int lrow = lane & 15;  // 0..15
  const int wRow = (wave >> 1) * 64;  // 0,64,128,192
  const int wCol = (wave & 1) * 64;   // 0,64
  const int slotk[2] = {quad ^ (lrow & 7), (4 + quad) ^ (lrow & 7)};

  // EPI=2: per-block row-sum inverse from psum partials (before any staging,
  // so the VGPR loads drain via compiler waits and don't perturb the
  // counted-vmcnt ledger below). Published to all waves by the prologue
  // LGKM0+BARRIER; read only at the epilogue (many barriers later).
  if (EPI == 2) {
    if (tid < 256) {
      const f32x4* p = (const f32x4*)(psum + (size_t)(mBase + tid) * 64);
      float s = 0.f;
#pragma unroll
      for (int ii = 0; ii < 16; ++ii) {
        f32x4 v = p[ii];
        s += v[0] + v[1] + v[2] + v[3];
      }
      inv_s[tid] = 1.0f / s;
    }
    LGKM0;
  }

  f32x4 acc[4][4];
#pragma unroll
  for (int i = 0; i < 4; ++i)
#pragma unroll
    for (int j = 0; j < 4; ++j) {
      f32x4 z = {0.f, 0.f, 0.f, 0.f};
      acc[i][j] = z;
    }

  bf16x8 aR[2][2], b0[2][2], b1[2][2];

  // prologue: tile0 {B, A.lo, A.hi} + B(1). (8 loads/thread; oldest 6 = tile0)
  stage_half(B, ldb, nBase, 0, &Bls[0][0], wave, lane);               // B(0)
  stage_half(A, lda, mBase, 0, &Als[0][0], wave, lane);               // A.lo(0)
  stage_half(A, lda, mBase + 128, 0, &Als[0][128 * 64], wave, lane);  // A.hi(0)
  stage_half(B, ldb, nBase, 64, &Bls[1][0], wave, lane);              // B(1)
  VMCNT2;  // tile0's 3 halves landed
  BARRIER;

  const int NI = K >> 7;  // 2 K-tiles (128 cols of K) per iteration
#pragma unroll 1
  for (int i = 0; i < NI; ++i) {
    const bool nl = (i + 1 < NI);
    const int kb = i * 128;
    // ---- phA0 (tile e in buf0)
    RD_A(0, 0);
    RD_B(0, 0, b0);
    RD_B(0, 1, b1);
    stage_half(A, lda, mBase, kb + 64, &Als[1][0], wave, lane);            // A.lo(o)
    stage_half(A, lda, mBase + 128, kb + 64, &Als[1][128 * 64], wave, lane); // A.hi(o)
    BARRIER; LGKM0; MMA16(0); BARRIER;
    // ---- phB0
    RD_A(0, 1);
    if (nl) {
      stage_half(B, ldb, nBase, kb + 128, &Bls[0][0], wave, lane);         // B(ne)
      VMCNT2;  // tile o's 3 halves landed
    } else {
      VMCNT0;  // tail: drain tile o's 6
    }
    BARRIER; LGKM0; MMA16(1); BARRIER;
    // ---- phA1 (tile o in buf1)
    RD_A(1, 0);
    RD_B(1, 0, b0);
    RD_B(1, 1, b1);
    if (nl) {
      stage_half(A, lda, mBase, kb + 128, &Als[0][0], wave, lane);           // A.lo(ne)
      stage_half(A, lda, mBase + 128, kb + 128, &Als[0][128 * 64], wave, lane); // A.hi(ne)
    }
    BARRIER; LGKM0; MMA16(0); BARRIER;
    // ---- phB1
    RD_A(1, 1);
    if (nl) {
      stage_half(B, ldb, nBase, kb + 192, &Bls[1][0], wave, lane);         // B(no)
      VMCNT2;  // tile ne's 3 halves landed
    }
    BARRIER; LGKM0; MMA16(1); BARRIER;
  }

  // epilogue. C/D layout (verified m89/m91): col=lane&15, row=quad*4+reg
  float rinv[4][4];
  if (EPI == 2) {
#pragma unroll
    for (int i = 0; i < 4; ++i)
#pragma unroll
      for (int r = 0; r < 4; ++r)
        rinv[i][r] = inv_s[wRow + i * 16 + quad * 4 + r];
  }
  float sp[4][4];  // EPI=1: per-row partial sums over this wave's 64 cols
  if (EPI == 1) {
#pragma unroll
    for (int i = 0; i < 4; ++i)
#pragma unroll
      for (int r = 0; r < 4; ++r) sp[i][r] = 0.f;
  }
#pragma unroll
  for (int j = 0; j < 4; ++j) {
    const int cn = nBase + wCol + j * 16 + lrow;
#pragma unroll
    for (int i = 0; i < 4; ++i) {
      const int rbase = mBase + wRow + i * 16 + quad * 4;
#pragma unroll
      for (int r = 0; r < 4; ++r) {
        if (EPI == 1) {
          bf16 eb = (bf16)__expf(acc[i][j][r] * scale);
          ((bf16*)C)[(size_t)(rbase + r) * ldc + cn] = eb;
          sp[i][r] += (float)eb;
        } else {
          ((float*)C)[(size_t)(rbase + r) * ldc + cn] = acc[i][j][r] * rinv[i][r];
        }
      }
    }
  }
  if (EPI == 1) {
    // reduce over the 16 lrow lanes (same rows, different 16-col groups)
#pragma unroll
    for (int i = 0; i < 4; ++i)
#pragma unroll
      for (int r = 0; r < 4; ++r) {
#pragma unroll
        for (int off = 1; off < 16; off <<= 1)
          sp[i][r] += __shfl_xor(sp[i][r], off, 64);
      }
    if (lrow == 0) {
      const int col64 = (nBase + wCol) >> 6;  // 0..63
#pragma unroll
      for (int i = 0; i < 4; ++i) {
        const int rbase = mBase + wRow + i * 16 + quad * 4;
#pragma unroll
        for (int r = 0; r < 4; ++r)
          psum[(size_t)(rbase + r) * 64 + col64] = sp[i][r];
      }
    }
  }
}

// QK + transpose merged dispatch:
//  blocks [0,512):   E = exp(q@k^T * scale) (BODY B, mt=16, nt=32) + psum
//  blocks [512,1024): transpose v_bf[S,D] -> vT_bf[D,S], 4 x 64x64 tiles each
__global__ __launch_bounds__(512, 2) void qk_gemm(
    const bf16* __restrict__ A, const bf16* __restrict__ B,
    bf16* __restrict__ E, float scale,
    const bf16* __restrict__ v, bf16* __restrict__ vT,
    float* __restrict__ psum) {
  if (blockIdx.x >= 512) {
    __shared__ bf16 ttile[64][66];
    const int t = threadIdx.x;
    const int col = t & 63;
    const int r8 = t >> 6;  // 0..7
    const int base = (blockIdx.x - 512) * 4;
#pragma unroll 1
    for (int t4 = 0; t4 < 4; ++t4) {
      const int id = base + t4;
      const int c0 = (id & 31) * 64;   // over D
      const int r0 = (id >> 5) * 64;   // over S
#pragma unroll
      for (int i = 0; i < 8; ++i) {
        int rr = i * 8 + r8;
        ttile[rr][col] = v[(size_t)(r0 + rr) * D_DIM + c0 + col];
      }
      __syncthreads();
#pragma unroll
      for (int i = 0; i < 8; ++i) {
        int rr = i * 8 + r8;
        vT[(size_t)(c0 + rr) * S_SEQ + r0 + col] = ttile[col][rr];
      }
      __syncthreads();
    }
    return;
  }
  int m, n;
  xcd_remap16(blockIdx.x, 32, m, n);
  gemm_body_4ph<1>(A, D_DIM, B, D_DIM, (void*)E, S_SEQ, scale, D_DIM,
                   m * 256, n * 128, psum);
}

// PV: out = (E @ vT^T) * inv[row], fp32 out. BODY B, mt=16, nt=16 -> 256
// blocks. inv computed in-block from psum (rowsum2 dispatch removed).
__global__ __launch_bounds__(512, 2) void pv_gemm(
    const bf16* __restrict__ E, const bf16* __restrict__ vT,
    float* __restrict__ out, float* __restrict__ psum) {
  int m, n;
  xcd_remap16(blockIdx.x, 16, m, n);
  gemm_body_4ph<2>(E, S_SEQ, vT, S_SEQ, (void*)out, D_DIM, 0.f, S_SEQ,
                   m * 256, n * 128, psum);
}

// merged projections: BODY A (r1 champion), mt=32, nt=16 -> 512 blocks/slice.
__global__ __launch_bounds__(256, 2) void proj_gemm(
    const bf16* __restrict__ xk, const bf16* __restrict__ xq,
    const bf16* __restrict__ xv,
    const bf16* __restrict__ Wk, const bf16* __restrict__ Wq,
    const bf16* __restrict__ Wv,
    const float* __restrict__ bk, const float* __restrict__ bq,
    const float* __restrict__ bv,
    bf16* __restrict__ ok, bf16* __restrict__ oq, bf16* __restrict__ ov) {
  const bf16 *A, *W;
  const float* b;
  bf16* o;
  switch (blockIdx.z) {
    case 0: A = xk; W = Wk; b = bk; o = ok; break;
    case 1: A = xq; W = Wq; b = bq; o = oq; break;
    default: A = xv; W = Wv; b = bv; o = ov; break;
  }
  int m, n;
  xcd_remap32(blockIdx.x, 16, m, n);
  gemm_body_sb<0>(A, E_DIM, W, E_DIM, (void*)o, D_DIM, b, 0.f, E_DIM,
                  m * 128, n * 128);
}

// ---------------------------------------------------------------------------
// launcher
// ---------------------------------------------------------------------------
extern "C" void kernel_launch(void* const* d_in, const int* in_sizes, int n_in,
                              void* d_out, int out_size, void* d_ws, size_t ws_size,
                              hipStream_t stream) {
  const float* key   = (const float*)d_in[0];
  const float* value = (const float*)d_in[1];
  const float* query = (const float*)d_in[2];
  const float* Wk = (const float*)d_in[3];
  const float* bk = (const float*)d_in[4];
  const float* Wq = (const float*)d_in[5];
  const float* bq = (const float*)d_in[6];
  const float* Wv = (const float*)d_in[7];
  const float* bv = (const float*)d_in[8];

  const size_t MB = 1ull << 20;
  char* ws = (char*)d_ws;
  // ws layout:
  //   0..48Mi   : key_bf/value_bf/query_bf (dead after proj; E+psum reuse)
  //   48..72Mi  : Wk_bf/Wq_bf/Wv_bf (dead after proj)
  //   72..120Mi : k_bf / q_bf / v_bf
  //   120..136Mi: vT_bf
  //   0..32Mi   : E bf16 [Q,S]       (reuses key/value region)
  //   34..35Mi  : psum fp32 [Q][64]  (reuses query region, dead post-proj)
  bf16* key_bf   = (bf16*)(ws + 0 * MB);
  bf16* value_bf = (bf16*)(ws + 16 * MB);
  bf16* query_bf = (bf16*)(ws + 32 * MB);
  bf16* Wk_bf    = (bf16*)(ws + 48 * MB);
  bf16* Wq_bf    = (bf16*)(ws + 56 * MB);
  bf16* Wv_bf    = (bf16*)(ws + 64 * MB);
  bf16* k_bf     = (bf16*)(ws + 72 * MB);
  bf16* q_bf     = (bf16*)(ws + 88 * MB);
  bf16* v_bf     = (bf16*)(ws + 104 * MB);
  bf16* vT_bf    = (bf16*)(ws + 120 * MB);
  bf16* E        = (bf16*)(ws + 0 * MB);
  float* psum    = (float*)(ws + 34 * MB);

  dim3 blk(256);
  dim3 blk512(512);

  // 1. all six casts, grid-stride (3072 blocks; was 49152 tiny blocks)
  cast6<<<dim3(512, 6), blk, 0, stream>>>(
      key, value, query, Wk, Wq, Wv,
      key_bf, value_bf, query_bf, Wk_bf, Wq_bf, Wv_bf);

  // 2. projections (BODY A): M=4096 (32 tiles), N=2048 (16) -> 512 blocks/slice
  proj_gemm<<<dim3(512, 1, 3), blk, 0, stream>>>(
      key_bf, query_bf, value_bf, Wk_bf, Wq_bf, Wv_bf, bk, bq, bv,
      k_bf, q_bf, v_bf);

  // 3. E = exp(q@k^T*scale) + psum partials, merged with v->vT transpose.
  const float scale = 0.022097086912079608f;  // 1/sqrt(2048)
  qk_gemm<<<dim3(1024), blk512, 0, stream>>>(q_bf, k_bf, E, scale,
                                             v_bf, vT_bf, psum);

  // 4. out = (E @ v) * inv[row] (BODY B; inv from psum in-block)
  pv_gemm<<<dim3(256), blk512, 0, stream>>>(E, vT_bf, (float*)d_out, psum);
}

// Round 10
// 439.924 us; speedup vs baseline: 1.0038x; 1.0038x over previous
//
#include <hip/hip_runtime.h>

// Problem constants (reference: S=Q=4096, E=D=2048, all fp32 in/out)
#define S_SEQ 4096
#define Q_SEQ 4096
#define E_DIM 2048
#define D_DIM 2048

typedef __bf16 bf16;
typedef __bf16 bf16x4 __attribute__((ext_vector_type(4)));
typedef __bf16 bf16x8 __attribute__((ext_vector_type(8)));
typedef float f32x4 __attribute__((ext_vector_type(4)));

// ---------------------------------------------------------------------------
// merged cast: 6 segments fp32 -> bf16, grid-stride.
// ---------------------------------------------------------------------------
__global__ __launch_bounds__(256) void cast6(
    const float* __restrict__ i0, const float* __restrict__ i1,
    const float* __restrict__ i2, const float* __restrict__ i3,
    const float* __restrict__ i4, const float* __restrict__ i5,
    bf16* __restrict__ o0, bf16* __restrict__ o1, bf16* __restrict__ o2,
    bf16* __restrict__ o3, bf16* __restrict__ o4, bf16* __restrict__ o5) {
  const float* in;
  bf16* out;
  int n4;
  switch (blockIdx.y) {
    case 0: in = i0; out = o0; n4 = (S_SEQ * E_DIM) / 4; break;
    case 1: in = i1; out = o1; n4 = (S_SEQ * E_DIM) / 4; break;
    case 2: in = i2; out = o2; n4 = (S_SEQ * E_DIM) / 4; break;
    case 3: in = i3; out = o3; n4 = (D_DIM * E_DIM) / 4; break;
    case 4: in = i4; out = o4; n4 = (D_DIM * E_DIM) / 4; break;
    default: in = i5; out = o5; n4 = (D_DIM * E_DIM) / 4; break;
  }
  const int stride = 512 * 256;
#pragma unroll 2
  for (int i = blockIdx.x * 256 + threadIdx.x; i < n4; i += stride) {
    float4 v = reinterpret_cast<const float4*>(in)[i];
    bf16x4 o;
    o[0] = (bf16)v.x; o[1] = (bf16)v.y; o[2] = (bf16)v.z; o[3] = (bf16)v.w;
    *reinterpret_cast<bf16x4*>(out + 4 * (size_t)i) = o;
  }
}

// ---------------------------------------------------------------------------
// async global->LDS 16B (wave-uniform lds base + lane*16 scatter)
// ---------------------------------------------------------------------------
__device__ __forceinline__ void async_copy16(const bf16* g, bf16* l) {
  __builtin_amdgcn_global_load_lds(
      (const __attribute__((address_space(1))) void*)g,
      (__attribute__((address_space(3))) void*)l, 16, 0, 0);
}

// ---------------------------------------------------------------------------
// XCD-aware tile remaps. Both bijective; 4(m) x 2(n) XCD grid.
// remap32: m-tiles of 128 (mt=32).  remap16: m-tiles of 256 (mt=16).
// ---------------------------------------------------------------------------
__device__ __forceinline__ void xcd_remap32(int id, int nt, int& m, int& n) {
  int xcd = id & 7;
  int lid = id >> 3;
  m = (xcd & 3) * 8 + (lid & 7);
  n = (xcd >> 2) * (nt >> 1) + (lid >> 3);
}
__device__ __forceinline__ void xcd_remap16(int id, int nt, int& m, int& n) {
  int xcd = id & 7;
  int lid = id >> 3;
  m = (xcd & 3) * 4 + (lid & 3);
  n = (xcd >> 2) * (nt >> 1) + (lid >> 2);
}

// ===========================================================================
// BODY A (champion, proj only — serves as in-session control): single-buffer
// 128x128, BK=64, 4 waves (2x2), wave tile 64x64. 32 KB LDS -> ~2.6
// blocks/CU. LDS-traffic/K-tile = 64KB (770cy) vs MFMA 621cy -> LDS-bound at
// ratio 1.24, ceiling MfmaUtil ~45-49% (measured r1/r6/r7/r9).
// ===========================================================================
template <int EPI>
__device__ __forceinline__ void gemm_body_sb(
    const bf16* __restrict__ A, int lda,
    const bf16* __restrict__ B, int ldb,
    void* __restrict__ C, int ldc,
    const float* __restrict__ aux, float scale, int K, int mBase, int nBase) {
  __shared__ __align__(16) bf16 Als[128 * 64];   // 16 KB
  __shared__ __align__(16) bf16 Bls[128 * 64];   // 16 KB

  const int tid  = threadIdx.x;
  const int wave = tid >> 6;
  const int lane = tid & 63;
  const int quad = lane >> 4;   // 0..3
  const int lrow = lane & 15;   // 0..15
  const int wRow = (wave >> 1) * 64;
  const int wCol = (wave & 1) * 64;

  f32x4 acc[4][4];
#pragma unroll
  for (int i = 0; i < 4; ++i)
#pragma unroll
    for (int j = 0; j < 4; ++j) {
      f32x4 z = {0.f, 0.f, 0.f, 0.f};
      acc[i][j] = z;
    }

  for (int k0 = 0; k0 < K; k0 += 64) {
#pragma unroll
    for (int c = 0; c < 4; ++c) {
      int chunk = c * 256 + tid;
      int row = chunk >> 3;
      int kc = (chunk & 7) ^ (row & 7);
      const bf16* g = A + (size_t)(mBase + row) * lda + k0 + kc * 8;
      async_copy16(g, Als + (size_t)(c * 256 + wave * 64) * 8);
    }
#pragma unroll
    for (int c = 0; c < 4; ++c) {
      int chunk = c * 256 + tid;
      int row = chunk >> 3;
      int kc = (chunk & 7) ^ (row & 7);
      const bf16* g = B + (size_t)(nBase + row) * ldb + k0 + kc * 8;
      async_copy16(g, Bls + (size_t)(c * 256 + wave * 64) * 8);
    }
    __syncthreads();  // drains vmcnt: LDS tiles ready

#pragma unroll
    for (int kk = 0; kk < 2; ++kk) {
      bf16x8 af[4], bfr[4];
#pragma unroll
      for (int i = 0; i < 4; ++i) {
        int r = wRow + i * 16 + lrow;
        int slot = (kk * 4 + quad) ^ (r & 7);
        af[i] = *(const bf16x8*)(Als + (size_t)r * 64 + slot * 8);
      }
#pragma unroll
      for (int j = 0; j < 4; ++j) {
        int r = wCol + j * 16 + lrow;
        int slot = (kk * 4 + quad) ^ (r & 7);
        bfr[j] = *(const bf16x8*)(Bls + (size_t)r * 64 + slot * 8);
      }
#pragma unroll
      for (int i = 0; i < 4; ++i)
#pragma unroll
        for (int j = 0; j < 4; ++j)
          acc[i][j] = __builtin_amdgcn_mfma_f32_16x16x32_bf16(af[i], bfr[j], acc[i][j], 0, 0, 0);
    }
    __syncthreads();  // compute done; safe to overwrite LDS next iter
  }

  // epilogue. C/D layout (verified m89/m91): col=lane&15, row=quad*4+reg
#pragma unroll
  for (int j = 0; j < 4; ++j) {
    const int cn = nBase + wCol + j * 16 + lrow;
    float bj = 0.f;
    if (EPI == 0) bj = aux[cn];
#pragma unroll
    for (int i = 0; i < 4; ++i) {
      const int rbase = mBase + wRow + i * 16 + quad * 4;
#pragma unroll
      for (int r = 0; r < 4; ++r) {
        if (EPI == 0)
          ((bf16*)C)[(size_t)(rbase + r) * ldc + cn] = (bf16)(acc[i][j][r] + bj);
      }
    }
  }
}

// ===========================================================================
// BODY C (r10, qk/pv): single-buffer 256x128, BK=64, 4 waves (2M x 2N),
// wave tile 128x64 (acc 8x4 f32x4 = 128 regs). SAME sync structure as BODY A
// (stage -> syncthreads -> ds_read+MFMA -> syncthreads), scaled geometry.
// Rationale (LDS-traffic arithmetic): per K-tile, LDS reads = A(32K)x2 +
// B(16K)x2 = 96 KB = 1130 cy @85B/cy vs MFMA 256 x 4.85 = 1241 cy -> ratio
// 0.91, COMPUTE-bound (BODY A/B were 1.24, LDS-bound — the 45% MfmaUtil
// wall). 48 KB LDS -> 2 blocks/CU (VGPR-limited), implicit overlap kept.
// Epilogues: EPI=1 bf16 exp(acc*scale) + psum partials; EPI=2 f32 acc*aux[row].
// ===========================================================================
template <int EPI>
__device__ __forceinline__ void gemm_body_c(
    const bf16* __restrict__ A, int lda,
    const bf16* __restrict__ B, int ldb,
    void* __restrict__ C, int ldc,
    const float* __restrict__ aux, float scale, int K, int mBase, int nBase,
    float* __restrict__ psum) {
  __shared__ __align__(16) bf16 Als[256 * 64];   // 32 KB
  __shared__ __align__(16) bf16 Bls[128 * 64];   // 16 KB

  const int tid  = threadIdx.x;
  const int wave = tid >> 6;
  const int lane = tid & 63;
  const int quad = lane >> 4;   // 0..3
  const int lrow = lane & 15;   // 0..15
  const int wRow = (wave >> 1) * 128;  // 0 or 128
  const int wCol = (wave & 1) * 64;    // 0 or 64

  f32x4 acc[8][4];
#pragma unroll
  for (int i = 0; i < 8; ++i)
#pragma unroll
    for (int j = 0; j < 4; ++j) {
      f32x4 z = {0.f, 0.f, 0.f, 0.f};
      acc[i][j] = z;
    }

  for (int k0 = 0; k0 < K; k0 += 64) {
    // stage A: 256 rows x 64 cols = 2048 chunks16, 8/thread (wave-contiguous)
#pragma unroll
    for (int c = 0; c < 8; ++c) {
      int chunk = c * 256 + tid;
      int row = chunk >> 3;                // 0..255
      int kc = (chunk & 7) ^ (row & 7);    // XOR-swizzled k-chunk
      const bf16* g = A + (size_t)(mBase + row) * lda + k0 + kc * 8;
      async_copy16(g, Als + (size_t)(c * 256 + wave * 64) * 8);
    }
    // stage B: 128 rows = 1024 chunks, 4/thread
#pragma unroll
    for (int c = 0; c < 4; ++c) {
      int chunk = c * 256 + tid;
      int row = chunk >> 3;
      int kc = (chunk & 7) ^ (row & 7);
      const bf16* g = B + (size_t)(nBase + row) * ldb + k0 + kc * 8;
      async_copy16(g, Bls + (size_t)(c * 256 + wave * 64) * 8);
    }
    __syncthreads();  // drain vmcnt: tiles ready

#pragma unroll
    for (int kk = 0; kk < 2; ++kk) {
      bf16x8 af[8], bfr[4];
#pragma unroll
      for (int i = 0; i < 8; ++i) {
        int r = wRow + i * 16 + lrow;
        int slot = (kk * 4 + quad) ^ (r & 7);
        af[i] = *(const bf16x8*)(Als + (size_t)r * 64 + slot * 8);
      }
#pragma unroll
      for (int j = 0; j < 4; ++j) {
        int r = wCol + j * 16 + lrow;
        int slot = (kk * 4 + quad) ^ (r & 7);
        bfr[j] = *(const bf16x8*)(Bls + (size_t)r * 64 + slot * 8);
      }
#pragma unroll
      for (int i = 0; i < 8; ++i)
#pragma unroll
        for (int j = 0; j < 4; ++j)
          acc[i][j] = __builtin_amdgcn_mfma_f32_16x16x32_bf16(af[i], bfr[j], acc[i][j], 0, 0, 0);
    }
    __syncthreads();
  }

  // epilogue. C/D layout: col=lane&15, row=quad*4+reg
  float rinv[8][4];
  if (EPI == 2) {
#pragma unroll
    for (int i = 0; i < 8; ++i)
#pragma unroll
      for (int r = 0; r < 4; ++r)
        rinv[i][r] = aux[mBase + wRow + i * 16 + quad * 4 + r];
  }
  float sp[8][4];
  if (EPI == 1) {
#pragma unroll
    for (int i = 0; i < 8; ++i)
#pragma unroll
      for (int r = 0; r < 4; ++r) sp[i][r] = 0.f;
  }
#pragma unroll
  for (int j = 0; j < 4; ++j) {
    const int cn = nBase + wCol + j * 16 + lrow;
#pragma unroll
    for (int i = 0; i < 8; ++i) {
      const int rbase = mBase + wRow + i * 16 + quad * 4;
#pragma unroll
      for (int r = 0; r < 4; ++r) {
        if (EPI == 1) {
          bf16 eb = (bf16)__expf(acc[i][j][r] * scale);
          ((bf16*)C)[(size_t)(rbase + r) * ldc + cn] = eb;
          sp[i][r] += (float)eb;
        } else {
          ((float*)C)[(size_t)(rbase + r) * ldc + cn] = acc[i][j][r] * rinv[i][r];
        }
      }
    }
  }
  if (EPI == 1) {
    // reduce over the 16 lrow-lanes (same rows, different 16-col groups)
#pragma unroll
    for (int i = 0; i < 8; ++i)
#pragma unroll
      for (int r = 0; r < 4; ++r) {
#pragma unroll
        for (int off = 1; off < 16; off <<= 1)
          sp[i][r] += __shfl_xor(sp[i][r], off, 64);
      }
    if (lrow == 0) {
      const int col64 = (nBase + wCol) >> 6;
#pragma unroll
      for (int i = 0; i < 8; ++i) {
        const int rbase = mBase + wRow + i * 16 + quad * 4;
#pragma unroll
        for (int r = 0; r < 4; ++r)
          psum[(size_t)(rbase + r) * 64 + col64] = sp[i][r];
      }
    }
  }
}

// QK + transpose merged dispatch (256 threads):
//  blocks [0,512):    E = exp(q@k^T * scale) (BODY C, mt=16, nt=32) + psum
//  blocks [512,1024): transpose v_bf[S,D] -> vT_bf[D,S], 4 x 64x64 tiles each
__global__ __launch_bounds__(256, 2) void qk_gemm(
    const bf16* __restrict__ A, const bf16* __restrict__ B,
    bf16* __restrict__ E, float scale,
    const bf16* __restrict__ v, bf16* __restrict__ vT,
    float* __restrict__ psum) {
  if (blockIdx.x >= 512) {
    __shared__ bf16 ttile[64][66];
    const int t = threadIdx.x;
    const int col = t & 63;
    const int r4 = t >> 6;  // 0..3
    const int base = (blockIdx.x - 512) * 4;
#pragma unroll 1
    for (int t4 = 0; t4 < 4; ++t4) {
      const int id = base + t4;
      const int c0 = (id & 31) * 64;   // over D
      const int r0 = (id >> 5) * 64;   // over S
#pragma unroll
      for (int i = 0; i < 16; ++i) {
        int rr = i * 4 + r4;
        ttile[rr][col] = v[(size_t)(r0 + rr) * D_DIM + c0 + col];
      }
      __syncthreads();
#pragma unroll
      for (int i = 0; i < 16; ++i) {
        int rr = i * 4 + r4;
        vT[(size_t)(c0 + rr) * S_SEQ + r0 + col] = ttile[col][rr];
      }
      __syncthreads();
    }
    return;
  }
  int m, n;
  xcd_remap16(blockIdx.x, 32, m, n);
  gemm_body_c<1>(A, D_DIM, B, D_DIM, (void*)E, S_SEQ, nullptr, scale, D_DIM,
                 m * 256, n * 128, psum);
}

// PV: out = (E @ vT^T) * inv[row], fp32 out. BODY C, mt=16, nt=16 -> 256 blocks.
__global__ __launch_bounds__(256, 2) void pv_gemm(
    const bf16* __restrict__ E, const bf16* __restrict__ vT,
    float* __restrict__ out, const float* __restrict__ inv) {
  int m, n;
  xcd_remap16(blockIdx.x, 16, m, n);
  gemm_body_c<2>(E, S_SEQ, vT, S_SEQ, (void*)out, D_DIM, inv, 0.f, S_SEQ,
                 m * 256, n * 128, nullptr);
}

// merged projections: BODY A (control), mt=32, nt=16 -> 512 blocks/slice.
__global__ __launch_bounds__(256, 2) void proj_gemm(
    const bf16* __restrict__ xk, const bf16* __restrict__ xq,
    const bf16* __restrict__ xv,
    const bf16* __restrict__ Wk, const bf16* __restrict__ Wq,
    const bf16* __restrict__ Wv,
    const float* __restrict__ bk, const float* __restrict__ bq,
    const float* __restrict__ bv,
    bf16* __restrict__ ok, bf16* __restrict__ oq, bf16* __restrict__ ov) {
  const bf16 *A, *W;
  const float* b;
  bf16* o;
  switch (blockIdx.z) {
    case 0: A = xk; W = Wk; b = bk; o = ok; break;
    case 1: A = xq; W = Wq; b = bq; o = oq; break;
    default: A = xv; W = Wv; b = bv; o = ov; break;
  }
  int m, n;
  xcd_remap32(blockIdx.x, 16, m, n);
  gemm_body_sb<0>(A, E_DIM, W, E_DIM, (void*)o, D_DIM, b, 0.f, E_DIM,
                  m * 128, n * 128);
}

// ---------------------------------------------------------------------------
// rowsum2: inv[r] = 1 / sum(psum[r, 0..63]). One row per thread; 1 MB read.
// ---------------------------------------------------------------------------
__global__ __launch_bounds__(256) void rowsum2(
    const float* __restrict__ psum, float* __restrict__ inv) {
  const int r = blockIdx.x * 256 + threadIdx.x;
  const f32x4* p = (const f32x4*)(psum + (size_t)r * 64);
  float s = 0.f;
#pragma unroll
  for (int i = 0; i < 16; ++i) {
    f32x4 v = p[i];
    s += v[0] + v[1] + v[2] + v[3];
  }
  inv[r] = 1.0f / s;
}

// ---------------------------------------------------------------------------
// launcher
// ---------------------------------------------------------------------------
extern "C" void kernel_launch(void* const* d_in, const int* in_sizes, int n_in,
                              void* d_out, int out_size, void* d_ws, size_t ws_size,
                              hipStream_t stream) {
  const float* key   = (const float*)d_in[0];
  const float* value = (const float*)d_in[1];
  const float* query = (const float*)d_in[2];
  const float* Wk = (const float*)d_in[3];
  const float* bk = (const float*)d_in[4];
  const float* Wq = (const float*)d_in[5];
  const float* bq = (const float*)d_in[6];
  const float* Wv = (const float*)d_in[7];
  const float* bv = (const float*)d_in[8];

  const size_t MB = 1ull << 20;
  char* ws = (char*)d_ws;
  // ws layout:
  //   0..48Mi   : key_bf/value_bf/query_bf (dead after proj; E+psum reuse)
  //   48..72Mi  : Wk_bf/Wq_bf/Wv_bf (dead after proj)
  //   72..120Mi : k_bf / q_bf / v_bf
  //   120..136Mi: vT_bf
  //   0..32Mi   : E bf16 [Q,S]       (reuses key/value region)
  //   34..35Mi  : psum fp32 [Q][64]  (reuses query region, dead post-proj)
  //   35Mi      : inv fp32 [Q]
  bf16* key_bf   = (bf16*)(ws + 0 * MB);
  bf16* value_bf = (bf16*)(ws + 16 * MB);
  bf16* query_bf = (bf16*)(ws + 32 * MB);
  bf16* Wk_bf    = (bf16*)(ws + 48 * MB);
  bf16* Wq_bf    = (bf16*)(ws + 56 * MB);
  bf16* Wv_bf    = (bf16*)(ws + 64 * MB);
  bf16* k_bf     = (bf16*)(ws + 72 * MB);
  bf16* q_bf     = (bf16*)(ws + 88 * MB);
  bf16* v_bf     = (bf16*)(ws + 104 * MB);
  bf16* vT_bf    = (bf16*)(ws + 120 * MB);
  bf16* E        = (bf16*)(ws + 0 * MB);
  float* psum    = (float*)(ws + 34 * MB);
  float* inv     = (float*)(ws + 35 * MB);

  dim3 blk(256);

  // 1. all six casts, grid-stride
  cast6<<<dim3(512, 6), blk, 0, stream>>>(
      key, value, query, Wk, Wq, Wv,
      key_bf, value_bf, query_bf, Wk_bf, Wq_bf, Wv_bf);

  // 2. projections (BODY A): M=4096 (32 tiles), N=2048 (16) -> 512 blocks/slice
  proj_gemm<<<dim3(512, 1, 3), blk, 0, stream>>>(
      key_bf, query_bf, value_bf, Wk_bf, Wq_bf, Wv_bf, bk, bq, bv,
      k_bf, q_bf, v_bf);

  // 3. E = exp(q@k^T*scale) + psum partials (BODY C) merged with v->vT
  //    transpose. qk: 16m x 32n = 512 blocks; transpose: 512 blocks x 4 tiles.
  const float scale = 0.022097086912079608f;  // 1/sqrt(2048)
  qk_gemm<<<dim3(1024), blk, 0, stream>>>(q_bf, k_bf, E, scale,
                                          v_bf, vT_bf, psum);

  // 4. inv[r] = 1/rowsum (1 MB of partials)
  rowsum2<<<dim3(16), blk, 0, stream>>>(psum, inv);

  // 5. out = (E @ v) * inv[row] (BODY C): 16m x 16n = 256 blocks
  pv_gemm<<<dim3(256), blk, 0, stream>>>(E, vT_bf, (float*)d_out, inv);
}

// Round 11
// 419.173 us; speedup vs baseline: 1.0535x; 1.0495x over previous
//
#include <hip/hip_runtime.h>

// Problem constants (reference: S=Q=4096, E=D=2048, all fp32 in/out)
#define S_SEQ 4096
#define Q_SEQ 4096
#define E_DIM 2048
#define D_DIM 2048

typedef __bf16 bf16;
typedef __bf16 bf16x4 __attribute__((ext_vector_type(4)));
typedef __bf16 bf16x8 __attribute__((ext_vector_type(8)));
typedef float f32x4 __attribute__((ext_vector_type(4)));

// ---------------------------------------------------------------------------
// merged cast: 6 segments fp32 -> bf16 (original r6 grid: one item/thread).
// Grid-stride variant measured ~+20us across two sessions — reverted.
// ---------------------------------------------------------------------------
__global__ __launch_bounds__(256) void cast6(
    const float* __restrict__ i0, const float* __restrict__ i1,
    const float* __restrict__ i2, const float* __restrict__ i3,
    const float* __restrict__ i4, const float* __restrict__ i5,
    bf16* __restrict__ o0, bf16* __restrict__ o1, bf16* __restrict__ o2,
    bf16* __restrict__ o3, bf16* __restrict__ o4, bf16* __restrict__ o5) {
  const float* in;
  bf16* out;
  int n4;
  switch (blockIdx.y) {
    case 0: in = i0; out = o0; n4 = (S_SEQ * E_DIM) / 4; break;
    case 1: in = i1; out = o1; n4 = (S_SEQ * E_DIM) / 4; break;
    case 2: in = i2; out = o2; n4 = (S_SEQ * E_DIM) / 4; break;
    case 3: in = i3; out = o3; n4 = (D_DIM * E_DIM) / 4; break;
    case 4: in = i4; out = o4; n4 = (D_DIM * E_DIM) / 4; break;
    default: in = i5; out = o5; n4 = (D_DIM * E_DIM) / 4; break;
  }
  int i = blockIdx.x * 256 + threadIdx.x;
  if (i < n4) {
    float4 v = reinterpret_cast<const float4*>(in)[i];
    bf16x4 o;
    o[0] = (bf16)v.x; o[1] = (bf16)v.y; o[2] = (bf16)v.z; o[3] = (bf16)v.w;
    *reinterpret_cast<bf16x4*>(out + 4 * (size_t)i) = o;
  }
}

// ---------------------------------------------------------------------------
// async global->LDS 16B (wave-uniform lds base + lane*16 scatter)
// ---------------------------------------------------------------------------
__device__ __forceinline__ void async_copy16(const bf16* g, bf16* l) {
  __builtin_amdgcn_global_load_lds(
      (const __attribute__((address_space(1))) void*)g,
      (__attribute__((address_space(3))) void*)l, 16, 0, 0);
}

// ---------------------------------------------------------------------------
// XCD-aware tile remaps. Both bijective; 4(m) x 2(n) XCD grid.
// ---------------------------------------------------------------------------
__device__ __forceinline__ void xcd_remap32(int id, int nt, int& m, int& n) {
  int xcd = id & 7;
  int lid = id >> 3;
  m = (xcd & 3) * 8 + (lid & 7);
  n = (xcd >> 2) * (nt >> 1) + (lid >> 3);
}
__device__ __forceinline__ void xcd_remap16(int id, int nt, int& m, int& n) {
  int xcd = id & 7;
  int lid = id >> 3;
  m = (xcd & 3) * 4 + (lid & 3);
  n = (xcd >> 2) * (nt >> 1) + (lid >> 2);
}

// ===========================================================================
// BODY A (proj, control): single-buffer 128x128, BK=64, 4 waves (2x2), wave
// tile 64x64. 32 KB LDS -> ~2.6 blocks/CU; implicit multi-block overlap.
// Measured 97-106 us / MfmaUtil 45-49% across sessions.
// ===========================================================================
template <int EPI>
__device__ __forceinline__ void gemm_body_sb(
    const bf16* __restrict__ A, int lda,
    const bf16* __restrict__ B, int ldb,
    void* __restrict__ C, int ldc,
    const float* __restrict__ aux, float scale, int K, int mBase, int nBase) {
  __shared__ __align__(16) bf16 Als[128 * 64];   // 16 KB
  __shared__ __align__(16) bf16 Bls[128 * 64];   // 16 KB

  const int tid  = threadIdx.x;
  const int wave = tid >> 6;
  const int lane = tid & 63;
  const int quad = lane >> 4;   // 0..3
  const int lrow = lane & 15;   // 0..15
  const int wRow = (wave >> 1) * 64;
  const int wCol = (wave & 1) * 64;

  f32x4 acc[4][4];
#pragma unroll
  for (int i = 0; i < 4; ++i)
#pragma unroll
    for (int j = 0; j < 4; ++j) {
      f32x4 z = {0.f, 0.f, 0.f, 0.f};
      acc[i][j] = z;
    }

  for (int k0 = 0; k0 < K; k0 += 64) {
#pragma unroll
    for (int c = 0; c < 4; ++c) {
      int chunk = c * 256 + tid;
      int row = chunk >> 3;
      int kc = (chunk & 7) ^ (row & 7);
      const bf16* g = A + (size_t)(mBase + row) * lda + k0 + kc * 8;
      async_copy16(g, Als + (size_t)(c * 256 + wave * 64) * 8);
    }
#pragma unroll
    for (int c = 0; c < 4; ++c) {
      int chunk = c * 256 + tid;
      int row = chunk >> 3;
      int kc = (chunk & 7) ^ (row & 7);
      const bf16* g = B + (size_t)(nBase + row) * ldb + k0 + kc * 8;
      async_copy16(g, Bls + (size_t)(c * 256 + wave * 64) * 8);
    }
    __syncthreads();  // drains vmcnt: LDS tiles ready

#pragma unroll
    for (int kk = 0; kk < 2; ++kk) {
      bf16x8 af[4], bfr[4];
#pragma unroll
      for (int i = 0; i < 4; ++i) {
        int r = wRow + i * 16 + lrow;
        int slot = (kk * 4 + quad) ^ (r & 7);
        af[i] = *(const bf16x8*)(Als + (size_t)r * 64 + slot * 8);
      }
#pragma unroll
      for (int j = 0; j < 4; ++j) {
        int r = wCol + j * 16 + lrow;
        int slot = (kk * 4 + quad) ^ (r & 7);
        bfr[j] = *(const bf16x8*)(Bls + (size_t)r * 64 + slot * 8);
      }
#pragma unroll
      for (int i = 0; i < 4; ++i)
#pragma unroll
        for (int j = 0; j < 4; ++j)
          acc[i][j] = __builtin_amdgcn_mfma_f32_16x16x32_bf16(af[i], bfr[j], acc[i][j], 0, 0, 0);
    }
    __syncthreads();
  }

  // epilogue. C/D layout (verified m89/m91): col=lane&15, row=quad*4+reg
#pragma unroll
  for (int j = 0; j < 4; ++j) {
    const int cn = nBase + wCol + j * 16 + lrow;
    float bj = 0.f;
    if (EPI == 0) bj = aux[cn];
#pragma unroll
    for (int i = 0; i < 4; ++i) {
      const int rbase = mBase + wRow + i * 16 + quad * 4;
#pragma unroll
      for (int r = 0; r < 4; ++r) {
        if (EPI == 0)
          ((bf16*)C)[(size_t)(rbase + r) * ldc + cn] = (bf16)(acc[i][j][r] + bj);
      }
    }
  }
}

// ===========================================================================
// BODY C (qk only): single-buffer 256x128, BK=64, 4 waves (2M x 2N), wave
// tile 128x64 (LDS-read/MFMA ratio 0.91 vs BODY A's 1.24). Requires >=2
// blocks/CU of grid (qk: 512 gemm blocks = 2/CU). r10 counters proved it
// FAILS grid-limited kernels (pv @256 blocks: 1 blk/CU -> MfmaUtil 25%);
// r9->r10 total arithmetic implies it HELPED qk by ~13us.
// EPI=1: bf16 exp(acc*scale) out + psum partials.
// ===========================================================================
template <int EPI>
__device__ __forceinline__ void gemm_body_c(
    const bf16* __restrict__ A, int lda,
    const bf16* __restrict__ B, int ldb,
    void* __restrict__ C, int ldc,
    float scale, int K, int mBase, int nBase,
    float* __restrict__ psum) {
  __shared__ __align__(16) bf16 Als[256 * 64];   // 32 KB
  __shared__ __align__(16) bf16 Bls[128 * 64];   // 16 KB

  const int tid  = threadIdx.x;
  const int wave = tid >> 6;
  const int lane = tid & 63;
  const int quad = lane >> 4;
  const int lrow = lane & 15;
  const int wRow = (wave >> 1) * 128;  // 0 or 128
  const int wCol = (wave & 1) * 64;    // 0 or 64

  f32x4 acc[8][4];
#pragma unroll
  for (int i = 0; i < 8; ++i)
#pragma unroll
    for (int j = 0; j < 4; ++j) {
      f32x4 z = {0.f, 0.f, 0.f, 0.f};
      acc[i][j] = z;
    }

  for (int k0 = 0; k0 < K; k0 += 64) {
#pragma unroll
    for (int c = 0; c < 8; ++c) {
      int chunk = c * 256 + tid;
      int row = chunk >> 3;
      int kc = (chunk & 7) ^ (row & 7);
      const bf16* g = A + (size_t)(mBase + row) * lda + k0 + kc * 8;
      async_copy16(g, Als + (size_t)(c * 256 + wave * 64) * 8);
    }
#pragma unroll
    for (int c = 0; c < 4; ++c) {
      int chunk = c * 256 + tid;
      int row = chunk >> 3;
      int kc = (chunk & 7) ^ (row & 7);
      const bf16* g = B + (size_t)(nBase + row) * ldb + k0 + kc * 8;
      async_copy16(g, Bls + (size_t)(c * 256 + wave * 64) * 8);
    }
    __syncthreads();

#pragma unroll
    for (int kk = 0; kk < 2; ++kk) {
      bf16x8 af[8], bfr[4];
#pragma unroll
      for (int i = 0; i < 8; ++i) {
        int r = wRow + i * 16 + lrow;
        int slot = (kk * 4 + quad) ^ (r & 7);
        af[i] = *(const bf16x8*)(Als + (size_t)r * 64 + slot * 8);
      }
#pragma unroll
      for (int j = 0; j < 4; ++j) {
        int r = wCol + j * 16 + lrow;
        int slot = (kk * 4 + quad) ^ (r & 7);
        bfr[j] = *(const bf16x8*)(Bls + (size_t)r * 64 + slot * 8);
      }
#pragma unroll
      for (int i = 0; i < 8; ++i)
#pragma unroll
        for (int j = 0; j < 4; ++j)
          acc[i][j] = __builtin_amdgcn_mfma_f32_16x16x32_bf16(af[i], bfr[j], acc[i][j], 0, 0, 0);
    }
    __syncthreads();
  }

  float sp[8][4];
#pragma unroll
  for (int i = 0; i < 8; ++i)
#pragma unroll
    for (int r = 0; r < 4; ++r) sp[i][r] = 0.f;
#pragma unroll
  for (int j = 0; j < 4; ++j) {
    const int cn = nBase + wCol + j * 16 + lrow;
#pragma unroll
    for (int i = 0; i < 8; ++i) {
      const int rbase = mBase + wRow + i * 16 + quad * 4;
#pragma unroll
      for (int r = 0; r < 4; ++r) {
        bf16 eb = (bf16)__expf(acc[i][j][r] * scale);
        ((bf16*)C)[(size_t)(rbase + r) * ldc + cn] = eb;
        sp[i][r] += (float)eb;
      }
    }
  }
#pragma unroll
  for (int i = 0; i < 8; ++i)
#pragma unroll
    for (int r = 0; r < 4; ++r) {
#pragma unroll
      for (int off = 1; off < 16; off <<= 1)
        sp[i][r] += __shfl_xor(sp[i][r], off, 64);
    }
  if (lrow == 0) {
    const int col64 = (nBase + wCol) >> 6;
#pragma unroll
    for (int i = 0; i < 8; ++i) {
      const int rbase = mBase + wRow + i * 16 + quad * 4;
#pragma unroll
      for (int r = 0; r < 4; ++r)
        psum[(size_t)(rbase + r) * 64 + col64] = sp[i][r];
    }
  }
}

// ===========================================================================
// BODY B (pv): 4-phase counted-vmcnt 256x128, BK=64, 8 waves (4x2), wave
// tile 64x64. 96 KB LDS, 8 waves/CU — intra-block wave parallelism covers
// the 1-block/CU grid (r6/r7: pv < 96us). EPI=2: f32 out, acc * aux[row].
// ===========================================================================
__device__ __forceinline__ void stage_half(const bf16* __restrict__ G, int ld,
                                           int grow0, int k0, bf16* lds,
                                           int wave, int lane) {
#pragma unroll
  for (int s = 0; s < 2; ++s) {
    int c = (wave * 2 + s) * 64 + lane;
    int row = c >> 3;
    int kc = (c & 7) ^ (row & 7);
    const bf16* g = G + (size_t)(grow0 + row) * ld + k0 + kc * 8;
    async_copy16(g, lds + (size_t)(wave * 2 + s) * 512);
  }
}

#define BARRIER __builtin_amdgcn_s_barrier()
#define LGKM0 asm volatile("s_waitcnt lgkmcnt(0)" ::: "memory")
#define VMCNT2 asm volatile("s_waitcnt vmcnt(2)" ::: "memory")
#define VMCNT0 asm volatile("s_waitcnt vmcnt(0)" ::: "memory")

#define RD_A(buf, IP)                                                         \
  _Pragma("unroll") for (int ii = 0; ii < 2; ++ii)                            \
  _Pragma("unroll") for (int kk = 0; kk < 2; ++kk)                            \
      aR[ii][kk] = *(const bf16x8*)(&Als[buf][(size_t)(wRow + ((IP)*2 + ii) * 16 + lrow) * 64 + slotk[kk] * 8]);

#define RD_B(buf, JP, dst)                                                    \
  _Pragma("unroll") for (int jj = 0; jj < 2; ++jj)                            \
  _Pragma("unroll") for (int kk = 0; kk < 2; ++kk)                            \
      dst[jj][kk] = *(const bf16x8*)(&Bls[buf][(size_t)(wCol + ((JP)*2 + jj) * 16 + lrow) * 64 + slotk[kk] * 8]);

#define MMA16(IP)                                                              \
  __builtin_amdgcn_s_setprio(1);                                               \
  _Pragma("unroll") for (int jj = 0; jj < 2; ++jj)                             \
  _Pragma("unroll") for (int ii = 0; ii < 2; ++ii)                             \
  _Pragma("unroll") for (int kk = 0; kk < 2; ++kk)                             \
      acc[(IP)*2 + ii][jj] = __builtin_amdgcn_mfma_f32_16x16x32_bf16(          \
          aR[ii][kk], b0[jj][kk], acc[(IP)*2 + ii][jj], 0, 0, 0);              \
  _Pragma("unroll") for (int jj = 0; jj < 2; ++jj)                             \
  _Pragma("unroll") for (int ii = 0; ii < 2; ++ii)                             \
  _Pragma("unroll") for (int kk = 0; kk < 2; ++kk)                             \
      acc[(IP)*2 + ii][2 + jj] = __builtin_amdgcn_mfma_f32_16x16x32_bf16(      \
          aR[ii][kk], b1[jj][kk], acc[(IP)*2 + ii][2 + jj], 0, 0, 0);          \
  __builtin_amdgcn_s_setprio(0)

template <int EPI>
__device__ __forceinline__ void gemm_body_4ph(
    const bf16* __restrict__ A, int lda,
    const bf16* __restrict__ B, int ldb,
    void* __restrict__ C, int ldc,
    const float* __restrict__ aux, float scale, int K, int mBase, int nBase) {
  __shared__ __align__(16) bf16 Als[2][256 * 64];  // 64 KB
  __shared__ __align__(16) bf16 Bls[2][128 * 64];  // 32 KB

  const int tid  = threadIdx.x;
  const int wave = tid >> 6;
  const int lane = tid & 63;
  const int quad = lane >> 4;
  const int lrow = lane & 15;
  const int wRow = (wave >> 1) * 64;
  const int wCol = (wave & 1) * 64;
  const int slotk[2] = {quad ^ (lrow & 7), (4 + quad) ^ (lrow & 7)};

  f32x4 acc[4][4];
#pragma unroll
  for (int i = 0; i < 4; ++i)
#pragma unroll
    for (int j = 0; j < 4; ++j) {
      f32x4 z = {0.f, 0.f, 0.f, 0.f};
      acc[i][j] = z;
    }

  bf16x8 aR[2][2], b0[2][2], b1[2][2];

  stage_half(B, ldb, nBase, 0, &Bls[0][0], wave, lane);               // B(0)
  stage_half(A, lda, mBase, 0, &Als[0][0], wave, lane);               // A.lo(0)
  stage_half(A, lda, mBase + 128, 0, &Als[0][128 * 64], wave, lane);  // A.hi(0)
  stage_half(B, ldb, nBase, 64, &Bls[1][0], wave, lane);              // B(1)
  VMCNT2;
  BARRIER;

  const int NI = K >> 7;
#pragma unroll 1
  for (int i = 0; i < NI; ++i) {
    const bool nl = (i + 1 < NI);
    const int kb = i * 128;
    // ---- phA0
    RD_A(0, 0);
    RD_B(0, 0, b0);
    RD_B(0, 1, b1);
    stage_half(A, lda, mBase, kb + 64, &Als[1][0], wave, lane);
    stage_half(A, lda, mBase + 128, kb + 64, &Als[1][128 * 64], wave, lane);
    BARRIER; LGKM0; MMA16(0); BARRIER;
    // ---- phB0
    RD_A(0, 1);
    if (nl) {
      stage_half(B, ldb, nBase, kb + 128, &Bls[0][0], wave, lane);
      VMCNT2;
    } else {
      VMCNT0;
    }
    BARRIER; LGKM0; MMA16(1); BARRIER;
    // ---- phA1
    RD_A(1, 0);
    RD_B(1, 0, b0);
    RD_B(1, 1, b1);
    if (nl) {
      stage_half(A, lda, mBase, kb + 128, &Als[0][0], wave, lane);
      stage_half(A, lda, mBase + 128, kb + 128, &Als[0][128 * 64], wave, lane);
    }
    BARRIER; LGKM0; MMA16(0); BARRIER;
    // ---- phB1
    RD_A(1, 1);
    if (nl) {
      stage_half(B, ldb, nBase, kb + 192, &Bls[1][0], wave, lane);
      VMCNT2;
    }
    BARRIER; LGKM0; MMA16(1); BARRIER;
  }

  // epilogue (EPI=2): f32 out, acc * aux[row]
  float rinv[4][4];
#pragma unroll
  for (int i = 0; i < 4; ++i)
#pragma unroll
    for (int r = 0; r < 4; ++r)
      rinv[i][r] = aux[mBase + wRow + i * 16 + quad * 4 + r];
#pragma unroll
  for (int j = 0; j < 4; ++j) {
    const int cn = nBase + wCol + j * 16 + lrow;
#pragma unroll
    for (int i = 0; i < 4; ++i) {
      const int rbase = mBase + wRow + i * 16 + quad * 4;
#pragma unroll
      for (int r = 0; r < 4; ++r)
        ((float*)C)[(size_t)(rbase + r) * ldc + cn] = acc[i][j][r] * rinv[i][r];
    }
  }
}

// QK + transpose merged dispatch (256 threads):
//  blocks [0,512):    E = exp(q@k^T * scale) (BODY C, mt=16, nt=32) + psum
//  blocks [512,1024): transpose v_bf[S,D] -> vT_bf[D,S], 4 x 64x64 tiles each
__global__ __launch_bounds__(256, 2) void qk_gemm(
    const bf16* __restrict__ A, const bf16* __restrict__ B,
    bf16* __restrict__ E, float scale,
    const bf16* __restrict__ v, bf16* __restrict__ vT,
    float* __restrict__ psum) {
  if (blockIdx.x >= 512) {
    __shared__ bf16 ttile[64][66];
    const int t = threadIdx.x;
    const int col = t & 63;
    const int r4 = t >> 6;
    const int base = (blockIdx.x - 512) * 4;
#pragma unroll 1
    for (int t4 = 0; t4 < 4; ++t4) {
      const int id = base + t4;
      const int c0 = (id & 31) * 64;
      const int r0 = (id >> 5) * 64;
#pragma unroll
      for (int i = 0; i < 16; ++i) {
        int rr = i * 4 + r4;
        ttile[rr][col] = v[(size_t)(r0 + rr) * D_DIM + c0 + col];
      }
      __syncthreads();
#pragma unroll
      for (int i = 0; i < 16; ++i) {
        int rr = i * 4 + r4;
        vT[(size_t)(c0 + rr) * S_SEQ + r0 + col] = ttile[col][rr];
      }
      __syncthreads();
    }
    return;
  }
  int m, n;
  xcd_remap16(blockIdx.x, 32, m, n);
  gemm_body_c<1>(A, D_DIM, B, D_DIM, (void*)E, S_SEQ, scale, D_DIM,
                 m * 256, n * 128, psum);
}

// PV: out = (E @ vT^T) * inv[row], fp32 out. BODY B (8 waves), 256 blocks.
__global__ __launch_bounds__(512, 2) void pv_gemm(
    const bf16* __restrict__ E, const bf16* __restrict__ vT,
    float* __restrict__ out, const float* __restrict__ inv) {
  int m, n;
  xcd_remap16(blockIdx.x, 16, m, n);
  gemm_body_4ph<2>(E, S_SEQ, vT, S_SEQ, (void*)out, D_DIM, inv, 0.f, S_SEQ,
                   m * 256, n * 128);
}

// merged projections: BODY A (control), mt=32, nt=16 -> 512 blocks/slice.
__global__ __launch_bounds__(256, 2) void proj_gemm(
    const bf16* __restrict__ xk, const bf16* __restrict__ xq,
    const bf16* __restrict__ xv,
    const bf16* __restrict__ Wk, const bf16* __restrict__ Wq,
    const bf16* __restrict__ Wv,
    const float* __restrict__ bk, const float* __restrict__ bq,
    const float* __restrict__ bv,
    bf16* __restrict__ ok, bf16* __restrict__ oq, bf16* __restrict__ ov) {
  const bf16 *A, *W;
  const float* b;
  bf16* o;
  switch (blockIdx.z) {
    case 0: A = xk; W = Wk; b = bk; o = ok; break;
    case 1: A = xq; W = Wq; b = bq; o = oq; break;
    default: A = xv; W = Wv; b = bv; o = ov; break;
  }
  int m, n;
  xcd_remap32(blockIdx.x, 16, m, n);
  gemm_body_sb<0>(A, E_DIM, W, E_DIM, (void*)o, D_DIM, b, 0.f, E_DIM,
                  m * 128, n * 128);
}

// ---------------------------------------------------------------------------
// rowsum2: inv[r] = 1 / sum(psum[r, 0..63]). One row per thread; 1 MB read.
// ---------------------------------------------------------------------------
__global__ __launch_bounds__(256) void rowsum2(
    const float* __restrict__ psum, float* __restrict__ inv) {
  const int r = blockIdx.x * 256 + threadIdx.x;
  const f32x4* p = (const f32x4*)(psum + (size_t)r * 64);
  float s = 0.f;
#pragma unroll
  for (int i = 0; i < 16; ++i) {
    f32x4 v = p[i];
    s += v[0] + v[1] + v[2] + v[3];
  }
  inv[r] = 1.0f / s;
}

// ---------------------------------------------------------------------------
// launcher
// ---------------------------------------------------------------------------
extern "C" void kernel_launch(void* const* d_in, const int* in_sizes, int n_in,
                              void* d_out, int out_size, void* d_ws, size_t ws_size,
                              hipStream_t stream) {
  const float* key   = (const float*)d_in[0];
  const float* value = (const float*)d_in[1];
  const float* query = (const float*)d_in[2];
  const float* Wk = (const float*)d_in[3];
  const float* bk = (const float*)d_in[4];
  const float* Wq = (const float*)d_in[5];
  const float* bq = (const float*)d_in[6];
  const float* Wv = (const float*)d_in[7];
  const float* bv = (const float*)d_in[8];

  const size_t MB = 1ull << 20;
  char* ws = (char*)d_ws;
  bf16* key_bf   = (bf16*)(ws + 0 * MB);
  bf16* value_bf = (bf16*)(ws + 16 * MB);
  bf16* query_bf = (bf16*)(ws + 32 * MB);
  bf16* Wk_bf    = (bf16*)(ws + 48 * MB);
  bf16* Wq_bf    = (bf16*)(ws + 56 * MB);
  bf16* Wv_bf    = (bf16*)(ws + 64 * MB);
  bf16* k_bf     = (bf16*)(ws + 72 * MB);
  bf16* q_bf     = (bf16*)(ws + 88 * MB);
  bf16* v_bf     = (bf16*)(ws + 104 * MB);
  bf16* vT_bf    = (bf16*)(ws + 120 * MB);
  bf16* E        = (bf16*)(ws + 0 * MB);
  float* psum    = (float*)(ws + 34 * MB);
  float* inv     = (float*)(ws + 35 * MB);

  dim3 blk(256);
  dim3 blk512(512);

  // 1. all six casts (original grid)
  cast6<<<dim3(8192, 6), blk, 0, stream>>>(
      key, value, query, Wk, Wq, Wv,
      key_bf, value_bf, query_bf, Wk_bf, Wq_bf, Wv_bf);

  // 2. projections (BODY A): 512 blocks/slice
  proj_gemm<<<dim3(512, 1, 3), blk, 0, stream>>>(
      key_bf, query_bf, value_bf, Wk_bf, Wq_bf, Wv_bf, bk, bq, bv,
      k_bf, q_bf, v_bf);

  // 3. E = exp(q@k^T*scale) + psum (BODY C) merged with v->vT transpose
  const float scale = 0.022097086912079608f;  // 1/sqrt(2048)
  qk_gemm<<<dim3(1024), blk, 0, stream>>>(q_bf, k_bf, E, scale,
                                          v_bf, vT_bf, psum);

  // 4. inv[r] = 1/rowsum (1 MB of partials)
  rowsum2<<<dim3(16), blk, 0, stream>>>(psum, inv);

  // 5. out = (E @ v) * inv[row] (BODY B, 8 waves): 256 blocks
  pv_gemm<<<dim3(256), blk512, 0, stream>>>(E, vT_bf, (float*)d_out, inv);
}